// Round 4
// baseline (432.864 us; speedup 1.0000x reference)
//
#include <hip/hip_runtime.h>
#include <math.h>

// V=100000, D=300, B=16384, NCTX=10, NNEG=20
#define DIM    300
#define CH     75           // float4 chunks per row (1200 B, 16B-aligned)
#define NCTX   10
#define NNEG   20
#define NROWS  (1 + NNEG)   // 21 out rows: [0]=center, [1..20]=negatives
#define BLOCK  256          // 4 waves/block, one sample per wave
#define G      7            // out-rows per load batch (3 batches of 7)

__device__ __forceinline__ float logsig_fast(float x) {
    // min(x,0) - log(1+exp(-|x|)) with native exp/log. rel err ~1e-6;
    // threshold is 0.29 absolute on a ~14.5 loss — orders of margin.
    return fminf(x, 0.f) - __logf(1.f + __expf(-fabsf(x)));
}
__device__ __forceinline__ float dot4(float4 a, float4 b) {
    return a.x * b.x + a.y * b.y + a.z * b.z + a.w * b.w;
}
__device__ __forceinline__ float4 add4(float4 a, float4 b) {
    return make_float4(a.x + b.x, a.y + b.y, a.z + b.z, a.w + b.w);
}

__global__ __launch_bounds__(BLOCK) void cbow_loss_kernel(
    const int*   __restrict__ ctx,     // [B, NCTX]
    const int*   __restrict__ center,  // [B]
    const int*   __restrict__ neg,     // [B, NNEG]
    const float* __restrict__ in_w,    // [V, D]
    const float* __restrict__ out_w,   // [V, D]
    float*       __restrict__ out,     // [1], zeroed on-stream
    int B, float inv_b)
{
    const int tid  = threadIdx.x;
    const int wave = tid >> 6;
    const int lane = tid & 63;
    const int b    = blockIdx.x * 4 + wave;   // one sample per wave
    if (b >= B) return;                       // wave-uniform

    // Each lane loads one of the 31 word indices; row addresses broadcast
    // via __shfl (v_readlane). No LDS, no barriers anywhere.
    int myidx = 0;
    if (lane < NCTX)              myidx = ctx[b * NCTX + lane];
    else if (lane == NCTX)        myidx = center[b];
    else if (lane < NCTX + NROWS) myidx = neg[b * NNEG + (lane - NCTX - 1)];

    // Chunk ownership: c1=lane (always valid), c2=64+lane (lanes 0..10).
    // Invalid lanes clamp-load chunk 74 (broadcast) and zero it via s1.
    const int   c1 = lane;
    const int   c2 = (64 + lane < CH) ? 64 + lane : CH - 1;
    const float w1 = (64 + lane < CH) ? 1.f : 0.f;

    // ---- Phase 1: ctx mean in registers. 20 independent loads.
    float4 a0 = make_float4(0.f, 0.f, 0.f, 0.f);
    float4 a1 = make_float4(0.f, 0.f, 0.f, 0.f);
    #pragma unroll
    for (int j = 0; j < NCTX; ++j) {
        const int w = __shfl(myidx, j, 64);
        const float4* row = (const float4*)(in_w + (long long)w * DIM);
        a0 = add4(a0, row[c1]);
        a1 = add4(a1, row[c2]);
    }
    const float s0 = 1.f / NCTX;
    const float s1 = w1 / NCTX;
    const float4 m0 = make_float4(a0.x * s0, a0.y * s0, a0.z * s0, a0.w * s0);
    const float4 m1 = make_float4(a1.x * s1, a1.y * s1, a1.z * s1, a1.w * s1);

    // ---- Phase 2: 21 per-lane partial dots, 3 batches of 7 rows
    // (14 independent 16B loads per batch).
    float p[NROWS];
    #pragma unroll
    for (int t = 0; t < 3; ++t) {
        float4 r0[G], r1[G];
        #pragma unroll
        for (int k = 0; k < G; ++k) {
            const int w = __shfl(myidx, NCTX + t * G + k, 64);
            const float4* row = (const float4*)(out_w + (long long)w * DIM);
            r0[k] = row[c1];
            r1[k] = row[c2];
        }
        #pragma unroll
        for (int k = 0; k < G; ++k)
            p[t * G + k] = dot4(r0[k], m0) + dot4(r1[k], m1);
    }

    // ---- Packed multi-value reduction: 44 shuffles for 21 sums (vs 21*6).
    // After each butterfly level the halves hold identical partials, so we
    // pack two dots per value slot, selected by the lane bit of that level.
    const bool B5 = lane & 32, B4 = lane & 16, B3 = lane & 8;
    const bool B2 = lane & 4,  B1 = lane & 2,  B0 = lane & 1;

    #pragma unroll
    for (int k = 0; k < NROWS; ++k) p[k] += __shfl_xor(p[k], 32, 64);
    float q[11];
    #pragma unroll
    for (int j = 0; j < 10; ++j) q[j] = B5 ? p[2 * j + 1] : p[2 * j];
    q[10] = p[20];
    #pragma unroll
    for (int j = 0; j < 11; ++j) q[j] += __shfl_xor(q[j], 16, 64);
    float r[6];
    #pragma unroll
    for (int i = 0; i < 5; ++i) r[i] = B4 ? q[2 * i + 1] : q[2 * i];
    r[5] = q[10];
    #pragma unroll
    for (int i = 0; i < 6; ++i) r[i] += __shfl_xor(r[i], 8, 64);
    float s[3];
    #pragma unroll
    for (int h = 0; h < 3; ++h) s[h] = B3 ? r[2 * h + 1] : r[2 * h];
    #pragma unroll
    for (int h = 0; h < 3; ++h) s[h] += __shfl_xor(s[h], 4, 64);
    float t0 = B2 ? s[1] : s[0];
    float t1 = s[2];
    t0 += __shfl_xor(t0, 2, 64);
    t1 += __shfl_xor(t1, 2, 64);
    float u = B1 ? t1 : t0;
    u += __shfl_xor(u, 1, 64);

    // Per-lane dot index + canonical-lane mask (21 canonical lanes total):
    //   B1=0            : k = 8*B2+4*B3+2*B4+B5   canon: B0=0   (16 lanes)
    //   B1=1,B3=0       : k = 16+2*B4+B5          canon: B0=B2=0 (4 lanes)
    //   B1=1,B3=1       : k = 20                  canon: lane==10
    int  k;
    bool canon;
    if (!B1)      { k = (B2 ? 8 : 0) + (B3 ? 4 : 0) + (B4 ? 2 : 0) + (B5 ? 1 : 0); canon = !B0; }
    else if (!B3) { k = 16 + (B4 ? 2 : 0) + (B5 ? 1 : 0); canon = !B0 && !B2; }
    else          { k = 20; canon = (lane == 10); }

    // ONE parallel log-sigmoid across lanes (k==0 is the positive score),
    // then a single 6-step butterfly for the wave total.
    float val = canon ? logsig_fast(k == 0 ? u : -u) : 0.f;
    #pragma unroll
    for (int off = 32; off > 0; off >>= 1)
        val += __shfl_xor(val, off, 64);

    if (lane == 0) atomicAdd(out, -val * inv_b);  // loss = -mean_b(...)
}

extern "C" void kernel_launch(void* const* d_in, const int* in_sizes, int n_in,
                              void* d_out, int out_size, void* d_ws, size_t ws_size,
                              hipStream_t stream) {
    const int*   ctx    = (const int*)  d_in[0];
    const int*   center = (const int*)  d_in[1];
    const int*   neg    = (const int*)  d_in[2];
    const float* in_w   = (const float*)d_in[3];
    const float* out_w  = (const float*)d_in[4];
    float*       out    = (float*)d_out;

    const int B = in_sizes[1];  // center_word is [B]

    hipMemsetAsync(out, 0, sizeof(float), stream);
    cbow_loss_kernel<<<(B + 3) / 4, BLOCK, 0, stream>>>(ctx, center, neg,
                                                        in_w, out_w, out,
                                                        B, 1.0f / (float)B);
}

// Round 5
// 420.882 us; speedup vs baseline: 1.0285x; 1.0285x over previous
//
#include <hip/hip_runtime.h>
#include <math.h>

// V=100000, D=300, B=16384, NCTX=10, NNEG=20
#define DIM    300
#define CH     75           // float4 chunks per row (1200 B, 16B-aligned)
#define NCTX   10
#define NNEG   20
#define NROWS  (1 + NNEG)   // 21 out rows: [0]=center, [1..20]=negatives
#define BLOCK  256          // 4 waves/block, one sample per wave

__device__ __forceinline__ float logsig_fast(float x) {
    // min(x,0) - log(1+exp(-|x|)) with native v_exp/v_log. abs err ~1e-6;
    // test threshold is 0.29 on a ~14.5 loss — orders of margin.
    return fminf(x, 0.f) - __logf(1.f + __expf(-fabsf(x)));
}
__device__ __forceinline__ float dot4(float4 a, float4 b) {
    return a.x * b.x + a.y * b.y + a.z * b.z + a.w * b.w;
}
__device__ __forceinline__ float4 add4(float4 a, float4 b) {
    return make_float4(a.x + b.x, a.y + b.y, a.z + b.z, a.w + b.w);
}

// One batch of NB out-rows: issue 2*NB independent 16B loads, per-lane dots,
// per-value butterfly, lane0 accumulates log-sigmoid terms.
// NB <= 11 keeps arrays register-resident under the 128-VGPR cap
// (R4 lesson: 21-element arrays get demoted to LDS — 17 KB/block, 262K bank
// conflicts, VALUBusy 5%. Never again.)
template <int NB>
__device__ __forceinline__ float batch_loss(int base, int myidx, int c1, int c2,
                                            float4 m0, float4 m1,
                                            const float* __restrict__ out_w,
                                            int lane) {
    float4 r0[NB], r1[NB];
    #pragma unroll
    for (int k = 0; k < NB; ++k) {
        const int w = __shfl(myidx, NCTX + base + k, 64);
        const float4* row = (const float4*)(out_w + (long long)w * DIM);
        r0[k] = row[c1];
        r1[k] = row[c2];
    }
    float p[NB];
    #pragma unroll
    for (int k = 0; k < NB; ++k)
        p[k] = dot4(r0[k], m0) + dot4(r1[k], m1);
    #pragma unroll
    for (int off = 32; off > 0; off >>= 1) {
        #pragma unroll
        for (int k = 0; k < NB; ++k)
            p[k] += __shfl_down(p[k], off, 64);
    }
    float loss = 0.f;
    if (lane == 0) {
        #pragma unroll
        for (int k = 0; k < NB; ++k) {
            const int i = base + k;
            loss += logsig_fast(i == 0 ? p[k] : -p[k]);
        }
    }
    return loss;
}

__global__ __launch_bounds__(BLOCK, 4) void cbow_loss_kernel(
    const int*   __restrict__ ctx,     // [B, NCTX]
    const int*   __restrict__ center,  // [B]
    const int*   __restrict__ neg,     // [B, NNEG]
    const float* __restrict__ in_w,    // [V, D]
    const float* __restrict__ out_w,   // [V, D]
    float*       __restrict__ out,     // [1], zeroed on-stream
    int B, float inv_b)
{
    const int tid  = threadIdx.x;
    const int wave = tid >> 6;
    const int lane = tid & 63;
    const int b    = blockIdx.x * 4 + wave;   // one sample per wave
    if (b >= B) return;                       // wave-uniform

    // Each lane holds one of the 31 word indices; row addresses broadcast
    // via __shfl (v_readlane). No LDS, no barriers anywhere.
    int myidx = 0;
    if (lane < NCTX)              myidx = ctx[b * NCTX + lane];
    else if (lane == NCTX)        myidx = center[b];
    else if (lane < NCTX + NROWS) myidx = neg[b * NNEG + (lane - NCTX - 1)];

    // Chunk ownership: c1=lane (always valid), c2=64+lane (lanes 0..10).
    // Invalid lanes clamp-load chunk 74 (same-line broadcast), zeroed via s1.
    const int   c1 = lane;
    const int   c2 = (64 + lane < CH) ? 64 + lane : CH - 1;
    const float w1 = (64 + lane < CH) ? 1.f : 0.f;

    // ---- Phase 1: ctx mean in registers. 20 independent loads.
    float4 a0 = make_float4(0.f, 0.f, 0.f, 0.f);
    float4 a1 = make_float4(0.f, 0.f, 0.f, 0.f);
    #pragma unroll
    for (int j = 0; j < NCTX; ++j) {
        const int w = __shfl(myidx, j, 64);
        const float4* row = (const float4*)(in_w + (long long)w * DIM);
        a0 = add4(a0, row[c1]);
        a1 = add4(a1, row[c2]);
    }
    const float s0 = 1.f / NCTX;
    const float s1 = w1 / NCTX;
    const float4 m0 = make_float4(a0.x * s0, a0.y * s0, a0.z * s0, a0.w * s0);
    const float4 m1 = make_float4(a1.x * s1, a1.y * s1, a1.z * s1, a1.w * s1);

    // ---- Phase 2: 21 dots in 2 deep batches (11 + 10 rows -> 22/20
    // independent loads in flight per batch).
    float loss = batch_loss<11>(0,  myidx, c1, c2, m0, m1, out_w, lane)
               + batch_loss<10>(11, myidx, c1, c2, m0, m1, out_w, lane);

    if (lane == 0) atomicAdd(out, -loss * inv_b);  // loss = -mean_b(...)
}

extern "C" void kernel_launch(void* const* d_in, const int* in_sizes, int n_in,
                              void* d_out, int out_size, void* d_ws, size_t ws_size,
                              hipStream_t stream) {
    const int*   ctx    = (const int*)  d_in[0];
    const int*   center = (const int*)  d_in[1];
    const int*   neg    = (const int*)  d_in[2];
    const float* in_w   = (const float*)d_in[3];
    const float* out_w  = (const float*)d_in[4];
    float*       out    = (float*)d_out;

    const int B = in_sizes[1];  // center_word is [B]

    hipMemsetAsync(out, 0, sizeof(float), stream);
    cbow_loss_kernel<<<(B + 3) / 4, BLOCK, 0, stream>>>(ctx, center, neg,
                                                        in_w, out_w, out,
                                                        B, 1.0f / (float)B);
}

// Round 6
// 293.418 us; speedup vs baseline: 1.4752x; 1.4344x over previous
//
#include <hip/hip_runtime.h>
#include <math.h>

// V=100000, D=300, B=16384, NCTX=10, NNEG=20
#define DIM    300
#define CH     75           // float4 chunks per row (1200 B, 16B-aligned)
#define NCTX   10
#define NNEG   20
#define NROWS  (1 + NNEG)   // 21 out rows: [0]=center, [1..20]=negatives
#define BLOCK  256          // 4 waves/block, one sample per wave
#define G      7            // out-rows per batch — R3's sweet spot.
// R4 lesson: >7-element arrays get demoted to LDS (17KB, 262K conflicts).
// R5 lesson: 11-deep batches + __launch_bounds__(,4) make the scheduler
// SERIALIZE loads (VGPR 36, VALUBusy 10%, 250us). Keep G=7, no min-waves hint.

__device__ __forceinline__ float logsig_fast(float x) {
    // min(x,0) - log(1+exp(-|x|)) with native v_exp/v_log. abs err ~1e-6;
    // test threshold is 0.29 on a ~14.5 loss — orders of margin.
    return fminf(x, 0.f) - __logf(1.f + __expf(-fabsf(x)));
}
__device__ __forceinline__ float dot4(float4 a, float4 b) {
    return a.x * b.x + a.y * b.y + a.z * b.z + a.w * b.w;
}
__device__ __forceinline__ float4 add4(float4 a, float4 b) {
    return make_float4(a.x + b.x, a.y + b.y, a.z + b.z, a.w + b.w);
}

__global__ __launch_bounds__(BLOCK) void cbow_loss_kernel(
    const int*   __restrict__ ctx,     // [B, NCTX]
    const int*   __restrict__ center,  // [B]
    const int*   __restrict__ neg,     // [B, NNEG]
    const float* __restrict__ in_w,    // [V, D]
    const float* __restrict__ out_w,   // [V, D]
    float*       __restrict__ out,     // [1], zeroed on-stream
    int B, float inv_b)
{
    __shared__ float wsum[4];

    const int tid  = threadIdx.x;
    const int wave = tid >> 6;
    const int lane = tid & 63;
    const int b    = blockIdx.x * 4 + wave;   // one sample per wave

    float loss = 0.f;
    if (b < B) {
        // Each lane holds one of the 31 word indices; row addresses broadcast
        // via __shfl (v_readlane). No barriers in the hot path.
        int myidx = 0;
        if (lane < NCTX)              myidx = ctx[b * NCTX + lane];
        else if (lane == NCTX)        myidx = center[b];
        else if (lane < NCTX + NROWS) myidx = neg[b * NNEG + (lane - NCTX - 1)];

        // Chunk ownership: c1=lane (always valid), c2=64+lane (lanes 0..10).
        // Invalid lanes clamp-load chunk 74 (same-line broadcast), zeroed via s1.
        const int   c1 = lane;
        const int   c2 = (64 + lane < CH) ? 64 + lane : CH - 1;
        const float w1 = (64 + lane < CH) ? 1.f : 0.f;

        // ---- Phase 1: ctx mean in registers. 20 independent loads.
        float4 a0 = make_float4(0.f, 0.f, 0.f, 0.f);
        float4 a1 = make_float4(0.f, 0.f, 0.f, 0.f);
        #pragma unroll
        for (int j = 0; j < NCTX; ++j) {
            const int w = __shfl(myidx, j, 64);
            const float4* row = (const float4*)(in_w + (long long)w * DIM);
            a0 = add4(a0, row[c1]);
            a1 = add4(a1, row[c2]);
        }
        const float s0 = 1.f / NCTX;
        const float s1 = w1 / NCTX;
        const float4 m0 = make_float4(a0.x * s0, a0.y * s0, a0.z * s0, a0.w * s0);
        const float4 m1 = make_float4(a1.x * s1, a1.y * s1, a1.z * s1, a1.w * s1);

        // ---- Phase 2: 21 dots in 3 batches of 7 (14 independent loads per
        // batch; batch t+1 loads overlap batch t reduction).
        #pragma unroll
        for (int t = 0; t < 3; ++t) {
            float4 r0[G], r1[G];
            #pragma unroll
            for (int k = 0; k < G; ++k) {
                const int w = __shfl(myidx, NCTX + t * G + k, 64);
                const float4* row = (const float4*)(out_w + (long long)w * DIM);
                r0[k] = row[c1];
                r1[k] = row[c2];
            }
            float p[G];
            #pragma unroll
            for (int k = 0; k < G; ++k)
                p[k] = dot4(r0[k], m0) + dot4(r1[k], m1);
            #pragma unroll
            for (int off = 32; off > 0; off >>= 1) {
                #pragma unroll
                for (int k = 0; k < G; ++k)
                    p[k] += __shfl_down(p[k], off, 64);
            }
            if (lane == 0) {
                #pragma unroll
                for (int k = 0; k < G; ++k) {
                    const int i = t * G + k;
                    loss += logsig_fast(i == 0 ? p[k] : -p[k]);
                }
            }
        }
    }

    if (lane == 0) wsum[wave] = loss;
    __syncthreads();
    if (tid == 0)
        atomicAdd(out, -(wsum[0] + wsum[1] + wsum[2] + wsum[3]) * inv_b);
}

extern "C" void kernel_launch(void* const* d_in, const int* in_sizes, int n_in,
                              void* d_out, int out_size, void* d_ws, size_t ws_size,
                              hipStream_t stream) {
    const int*   ctx    = (const int*)  d_in[0];
    const int*   center = (const int*)  d_in[1];
    const int*   neg    = (const int*)  d_in[2];
    const float* in_w   = (const float*)d_in[3];
    const float* out_w  = (const float*)d_in[4];
    float*       out    = (float*)d_out;

    const int B = in_sizes[1];  // center_word is [B]

    hipMemsetAsync(out, 0, sizeof(float), stream);
    cbow_loss_kernel<<<(B + 3) / 4, BLOCK, 0, stream>>>(ctx, center, neg,
                                                        in_w, out_w, out,
                                                        B, 1.0f / (float)B);
}